// Round 4
// baseline (937.003 us; speedup 1.0000x reference)
//
#include <hip/hip_runtime.h>

typedef __attribute__((ext_vector_type(4))) float floatx4;

#define HW   4096
#define CIN  512
#define CODE 256
#define MEM  20
#define NCLS 4
#define NB   32

// ---------------------------------------------------------------------------
// Kernel 1: x = Wp @ feats + bp  (fp32 VALU GEMM, per batch 256x512 @ 512x4096)
// Tile: 64(o) x 256(n), 256 threads, 8x8 microtile.
// Writes x into out[b][256+o][n] (concat second half).
// ---------------------------------------------------------------------------
__global__ __launch_bounds__(256) void gemm_proj_f32(
    const float* __restrict__ feats,
    const float* __restrict__ Wp,
    const float* __restrict__ bp,
    float* __restrict__ out)
{
    const int b  = blockIdx.z;
    const int n0 = blockIdx.x * 256;
    const int o0 = blockIdx.y * 64;
    const int tid = threadIdx.x;

    __shared__ float Asf[32][68];    // [k][o], row = 272 B (16B-aligned)
    __shared__ float Bsf[32][260];   // [k][n], row = 1040 B (16B-aligned)

    float acc[8][8];
#pragma unroll
    for (int i = 0; i < 8; ++i)
#pragma unroll
        for (int j = 0; j < 8; ++j) acc[i][j] = 0.f;

    const int og = tid >> 5;         // 0..7   -> o = og*8
    const int ng = tid & 31;         // 0..31  -> n = ng*8

    const int sa_o = tid >> 2;       // 0..63
    const int sa_k = (tid & 3) * 8;  // 0,8,16,24
    const int sb_k = tid >> 3;       // 0..31
    const int sb_n = (tid & 7) * 32; // 0..224

    for (int k0 = 0; k0 < CIN; k0 += 32) {
        floatx4 av0 = *(const floatx4*)(Wp + (size_t)(o0 + sa_o) * CIN + k0 + sa_k);
        floatx4 av1 = *(const floatx4*)(Wp + (size_t)(o0 + sa_o) * CIN + k0 + sa_k + 4);
        floatx4 bv[8];
        const float* fp = feats + ((size_t)b * CIN + k0 + sb_k) * HW + n0 + sb_n;
#pragma unroll
        for (int q = 0; q < 8; ++q) bv[q] = *(const floatx4*)(fp + q * 4);

        __syncthreads();                       // finish reads of previous tiles
#pragma unroll
        for (int j = 0; j < 4; ++j) Asf[sa_k + j][sa_o] = av0[j];
#pragma unroll
        for (int j = 0; j < 4; ++j) Asf[sa_k + 4 + j][sa_o] = av1[j];
#pragma unroll
        for (int q = 0; q < 8; ++q)
            *(floatx4*)&Bsf[sb_k][sb_n + q * 4] = bv[q];
        __syncthreads();

#pragma unroll 8
        for (int k = 0; k < 32; ++k) {
            floatx4 a0 = *(const floatx4*)&Asf[k][og * 8];
            floatx4 a1 = *(const floatx4*)&Asf[k][og * 8 + 4];
            floatx4 b0 = *(const floatx4*)&Bsf[k][ng * 8];
            floatx4 b1 = *(const floatx4*)&Bsf[k][ng * 8 + 4];
#pragma unroll
            for (int i = 0; i < 4; ++i)
#pragma unroll
                for (int j = 0; j < 4; ++j) {
                    acc[i][j]         += a0[i] * b0[j];
                    acc[i][j + 4]     += a0[i] * b1[j];
                    acc[i + 4][j]     += a1[i] * b0[j];
                    acc[i + 4][j + 4] += a1[i] * b1[j];
                }
        }
    }

#pragma unroll
    for (int i = 0; i < 8; ++i) {
        const int o = o0 + og * 8 + i;
        const float bias = bp[o];
        float* orow = out + ((size_t)b * 2 * CODE + CODE + o) * HW + n0 + ng * 8;
        floatx4 s0, s1;
#pragma unroll
        for (int j = 0; j < 4; ++j) { s0[j] = acc[i][j] + bias; s1[j] = acc[i][j + 4] + bias; }
        *(floatx4*)orow       = s0;
        *(floatx4*)(orow + 4) = s1;
    }
}

// ---------------------------------------------------------------------------
// Kernel 2: feat[b][c] = mean_n( x[b][c][n] * preds[b][n] )  -> fp32 ws
// grid (16 c-chunks, 32 b); preds staged in LDS once per block.
// ---------------------------------------------------------------------------
__global__ __launch_bounds__(256) void featmean_kernel(
    const float* __restrict__ preds,
    const float* __restrict__ out,
    float* __restrict__ featbuf)
{
    const int c0 = blockIdx.x * 16;
    const int b  = blockIdx.y;
    const int tid = threadIdx.x;
    const int w = tid >> 6, lane = tid & 63;

    __shared__ float sp[HW];
    const float* prow = preds + (size_t)b * HW;
#pragma unroll
    for (int j = 0; j < 4; ++j)
        *(floatx4*)&sp[tid * 4 + j * 1024] = *(const floatx4*)(prow + tid * 4 + j * 1024);
    __syncthreads();

    for (int cc = 0; cc < 4; ++cc) {
        const int c = c0 + w * 4 + cc;
        const float* xrow = out + ((size_t)b * 2 * CODE + CODE + c) * HW;
        float s = 0.f;
#pragma unroll 4
        for (int j = 0; j < 16; ++j) {
            floatx4 xv = *(const floatx4*)(xrow + lane * 4 + j * 256);
            floatx4 pv = *(const floatx4*)&sp[lane * 4 + j * 256];
            s += xv[0] * pv[0] + xv[1] * pv[1] + xv[2] * pv[2] + xv[3] * pv[3];
        }
        for (int off = 32; off > 0; off >>= 1) s += __shfl_down(s, off, 64);
        if (lane == 0) featbuf[b * CODE + c] = s * (1.f / HW);
    }
}

// ---------------------------------------------------------------------------
// Kernel 3: sequential EMA queue update (single block). qbuf = fp32 queue copy.
// upd[m][c] = logit[m]*f[c] / max(|logit[m]|*||f||, 1e-12); q[l]=0.9q[l]+0.1upd
// ---------------------------------------------------------------------------
__global__ __launch_bounds__(256) void scan_kernel(
    const float* __restrict__ queue_in,
    const float* __restrict__ featbuf,
    const int* __restrict__ labels,
    const int* __restrict__ flag,
    float* __restrict__ qbuf)
{
    const int tid = threadIdx.x;
    for (int i = tid; i < NCLS * MEM * CODE; i += 256)
        qbuf[i] = queue_in[i];
    __syncthreads();
    if (*flag != 1) return;

    __shared__ float sf[CODE];
    __shared__ float sred[256];
    __shared__ float slog[MEM];
    __shared__ float scoef[MEM];
    __shared__ float snorm;

    const int w = tid >> 6, lane = tid & 63;

    for (int b = 0; b < NB; ++b) {
        const int l = labels[b] & 3;           // labels are 0..3
        float f = featbuf[b * CODE + tid];
        sf[tid] = f;
        sred[tid] = f * f;
        __syncthreads();
        for (int st = 128; st > 0; st >>= 1) {
            if (tid < st) sred[tid] += sred[tid + st];
            __syncthreads();
        }
        if (tid == 0) snorm = sqrtf(sred[0]);
        __syncthreads();

        float* qrow = qbuf + (size_t)l * MEM * CODE;
        for (int mm = 0; mm < 5; ++mm) {
            int m = w * 5 + mm;
            float p = 0.f;
#pragma unroll
            for (int j = 0; j < 4; ++j) {
                int c = lane + 64 * j;
                p += qrow[m * CODE + c] * sf[c];
            }
            for (int off = 32; off > 0; off >>= 1) p += __shfl_down(p, off, 64);
            if (lane == 0) slog[m] = p;
        }
        __syncthreads();
        if (tid < MEM) {
            float lg = slog[tid];
            float denom = fmaxf(fabsf(lg) * snorm, 1e-12f);
            scoef[tid] = 0.1f * lg / denom;
        }
        __syncthreads();
        for (int m = 0; m < MEM; ++m) {
            int idx = m * CODE + tid;
            qrow[idx] = 0.9f * qrow[idx] + scoef[m] * sf[tid];
        }
        __syncthreads();
    }
}

// ---------------------------------------------------------------------------
// Kernel 4: attention. logit[m][n] = sum_c q[m][c] x[c][n]; softmax over m;
// new_feat[c][n] = sum_m q[m][c] attn[m][n] -> out[b][c][n] (first half)
// ---------------------------------------------------------------------------
__global__ __launch_bounds__(256) void attn_kernel(
    const float* __restrict__ qbuf,
    const int* __restrict__ labels,
    float* __restrict__ out)
{
    const int b = blockIdx.y;
    const int n = blockIdx.x * 256 + threadIdx.x;
    const int l = labels[b] & 3;

    __shared__ float sq[MEM * CODE];
    for (int i = threadIdx.x; i < MEM * CODE; i += 256)
        sq[i] = qbuf[(size_t)l * MEM * CODE + i];
    __syncthreads();

    const float* xb = out + ((size_t)b * 2 * CODE + CODE) * HW;

    float lg[MEM];
#pragma unroll
    for (int m = 0; m < MEM; ++m) lg[m] = 0.f;

    for (int c = 0; c < CODE; ++c) {
        float xv = xb[(size_t)c * HW + n];
#pragma unroll
        for (int m = 0; m < MEM; ++m) lg[m] += sq[m * CODE + c] * xv;
    }

    float mx = lg[0];
#pragma unroll
    for (int m = 1; m < MEM; ++m) mx = fmaxf(mx, lg[m]);
    float s = 0.f;
#pragma unroll
    for (int m = 0; m < MEM; ++m) { lg[m] = __expf(lg[m] - mx); s += lg[m]; }
    const float inv = 1.f / s;

    float* ob = out + (size_t)b * 2 * CODE * HW;
    for (int c = 0; c < CODE; ++c) {
        float acc = 0.f;
#pragma unroll
        for (int m = 0; m < MEM; ++m) acc += sq[m * CODE + c] * lg[m];
        ob[(size_t)c * HW + n] = acc * inv;
    }
}

// ---------------------------------------------------------------------------
extern "C" void kernel_launch(void* const* d_in, const int* in_sizes, int n_in,
                              void* d_out, int out_size, void* d_ws, size_t ws_size,
                              hipStream_t stream)
{
    const float* feats  = (const float*)d_in[0];
    const float* preds  = (const float*)d_in[1];
    const int*   labels = (const int*)d_in[2];
    const int*   flag   = (const int*)d_in[3];
    const float* queue  = (const float*)d_in[4];
    const float* Wp     = (const float*)d_in[5];
    const float* bp     = (const float*)d_in[6];
    float* out = (float*)d_out;

    float* featbuf = (float*)d_ws;                 // 32*256 fp32
    float* qbuf    = featbuf + NB * CODE;          // 4*20*256 fp32

    gemm_proj_f32<<<dim3(HW / 256, CODE / 64, NB), 256, 0, stream>>>(feats, Wp, bp, out);
    featmean_kernel<<<dim3(16, NB), 256, 0, stream>>>(preds, out, featbuf);
    scan_kernel<<<1, 256, 0, stream>>>(queue, featbuf, labels, flag, qbuf);
    attn_kernel<<<dim3(HW / 256, NB), 256, 0, stream>>>(qbuf, labels, out);
}